// Round 4
// baseline (1351.069 us; speedup 1.0000x reference)
//
#include <hip/hip_runtime.h>
#include <hip/hip_bf16.h>

// TreeHopNode: h = q - rep + (per-head MLP(sigmoid(Qh*Kh/16)*Vh)) @ Ws
// N=65536, E=1024, H=4, G=256, MLP=256. All GEMMs in bf16 MFMA, f32 accum.
//
// R4: all GEMMs moved to 256x256-tile, 8-wave, BK=64, double-buffered LDS,
// counted-vmcnt phase schedule (m201 regime: 384B LDS per MFMA vs 1KB in the
// 128^2 m97 structure, which is LDS-issue-bound at ~30% MfmaUtil).
// Phase G: stage group G+3 (vmcnt stays at 12, never drains in-loop),
// raw barrier, 12 swizzled ds_read_b128, setprio(1), 32 MFMA, setprio(0),
// raw barrier. Groups = 32-wide K slices; LDS region cycle of 4.

typedef __attribute__((ext_vector_type(8))) short bf16x8;
typedef __attribute__((ext_vector_type(4))) float f32x4;
typedef __attribute__((ext_vector_type(4))) short short4v;

static __device__ __forceinline__ short f2b(float x) {
  __hip_bfloat16 h = __float2bfloat16(x);
  return __builtin_bit_cast(short, h);
}
static __device__ __forceinline__ float b2f(short s) {
  unsigned u = ((unsigned)(unsigned short)s) << 16;
  return __builtin_bit_cast(float, u);
}

// Stage one [256 rows x 32 k] bf16 half-tile into linear LDS [256][32].
// global_load_lds: LDS dest = wave-uniform base + lane*16B -> lane l covers
// row r0 + l/4, granule l&3 (granule = 8 shorts = 16B). Source granule is
// pre-swizzled (l&3)^(row&3) so LDS granule g of row r holds global granule
// g^(r&3) (involution, matches the read-side XOR).
static __device__ __forceinline__ void stage_half(
    const short* __restrict__ g, long ld, short* ldsbase, int wave, int lane)
{
  const int rw = lane >> 2;                     // 0..15 within wave's row block
  const int gsw = (lane & 3) ^ (rw & 3);        // swizzled source granule
  #pragma unroll
  for (int j = 0; j < 2; ++j) {
    const int r0 = j * 128 + wave * 16;         // wave-uniform dest row
    __builtin_amdgcn_global_load_lds(
        (const __attribute__((address_space(1))) void*)(g + (long)(r0 + rw) * ld + (gsw << 3)),
        (__attribute__((address_space(3))) void*)(ldsbase + r0 * 32),
        16, 0, 0);
  }
}

// ---------------- convert f32 -> bf16, vectorized ----------------
__global__ void cvt_bf16(const float* __restrict__ in, short* __restrict__ out, long n) {
  long i = ((long)blockIdx.x * blockDim.x + threadIdx.x) * 4;
  const long stride = (long)gridDim.x * blockDim.x * 4;
  for (; i < n; i += stride) {
    float4 v = *(const float4*)(in + i);
    short4v o = { f2b(v.x), f2b(v.y), f2b(v.z), f2b(v.w) };
    *(short4v*)(out + i) = o;
  }
}

// ---------------- transpose + convert weights ----------------
__global__ void prep_weights(
    const float* __restrict__ Wq, const float* __restrict__ Wk, const float* __restrict__ Wv,
    const float* __restrict__ W1, const float* __restrict__ W2, const float* __restrict__ Ws,
    short* __restrict__ wqt, short* __restrict__ wkt, short* __restrict__ wvt,
    short* __restrict__ w1t, short* __restrict__ w2t, short* __restrict__ wst)
{
  const int job = blockIdx.z;
  const float* src; short* dst; int R, C;
  if (job < 3)       { src = (job==0)?Wq:((job==1)?Wk:Wv); dst = (job==0)?wqt:((job==1)?wkt:wvt); R = 1024; C = 1024; }
  else if (job == 3) { src = Ws; dst = wst; R = 1024; C = 1024; }
  else if (job < 8)  { int h = job-4; src = W1 + h*65536; dst = w1t + h*65536; R = 256; C = 256; }
  else               { int h = job-8; src = W2 + h*65536; dst = w2t + h*65536; R = 256; C = 256; }
  const int c0 = blockIdx.x * 32, r0 = blockIdx.y * 32;
  if (c0 >= C || r0 >= R) return;
  __shared__ float t[32][33];
  for (int i = threadIdx.y; i < 32; i += 8)
    t[i][threadIdx.x] = src[(long)(r0 + i) * C + c0 + threadIdx.x];
  __syncthreads();
  for (int i = threadIdx.y; i < 32; i += 8)
    dst[(long)(c0 + i) * R + r0 + threadIdx.x] = f2b(t[threadIdx.x][i]);
}

// ---------------- 256x256-tile bf16 GEMM, counted-vmcnt pipeline ----------
// C = ep(A @ Bt^T); Bt stored [col][k]. blockIdx.z batches heads (strides).
// GATE==1: out = sigmoid(b2f(eg[gi]) * acc / 16)   (eg may alias out)
// GATE==2: out = b2f(eg[gi]) * acc
// RESID:   f32 out = q - rep + acc
// SWZ:     XCD-chunk block swizzle (requires gridDim.x*gridDim.y % 8 == 0)
template <int KDIM, int GATE, bool RELU, bool BIAS, bool RESID, bool SWZ>
__global__ __launch_bounds__(512, 2) void gemm_bf16(
    const short* __restrict__ A, long lda, long zsa,
    const short* __restrict__ Bt, long ldb, long zsb,
    void* __restrict__ outv, long ldc, long zsc,
    const float* __restrict__ bias, long zsbias,
    const short* __restrict__ eg,
    const float* __restrict__ q, const float* __restrict__ rep)
{
  // LDS: [parity 2][kh 2][256][32] shorts for A and B = 64KB each, 128KB tot
  __shared__ __align__(16) short lA[32768];
  __shared__ __align__(16) short lB[32768];
  const int lane = threadIdx.x & 63, wave = threadIdx.x >> 6;
  const int wm = wave >> 2, wn = wave & 3;       // 2M x 4N wave grid
  int bx = blockIdx.x, by = blockIdx.y;
  if (SWZ) {
    const int nbx = gridDim.x;
    const int flat = by * nbx + bx;
    const int chunk = (int)(gridDim.x * gridDim.y) >> 3;
    const int fid = (flat & 7) * chunk + (flat >> 3);
    bx = fid % nbx; by = fid / nbx;
  }
  const long bm = (long)by * 256;
  const int  bn = bx * 256;
  const int  zi = blockIdx.z;

  const short* Ab = A + (long)zi * zsa + bm * lda;
  const short* Bb = Bt + (long)zi * zsb + (long)bn * ldb;

  constexpr int NG = KDIM / 32;   // 32-wide k groups; one phase per group

  // prologue: stage groups 0,1,2 (regions (p,kh) = (0,0),(0,1),(1,0))
  #pragma unroll
  for (int S = 0; S < 3; ++S) {
    short* aD = lA + ((S >> 1) & 1) * 16384 + (S & 1) * 8192;
    short* bD = lB + ((S >> 1) & 1) * 16384 + (S & 1) * 8192;
    stage_half(Ab + S * 32, lda, aD, wave, lane);
    stage_half(Bb + S * 32, ldb, bD, wave, lane);
  }

  f32x4 acc[8][4] = {};
  const int g0 = lane >> 4;          // k-octet 0..3 within the 32-k group

  for (int G = 0; G < NG; ++G) {
    // stage group G+3 (clamped; redundant same-byte restage at tail is benign)
    {
      const int S = (G + 3 < NG) ? (G + 3) : (NG - 1);
      short* aD = lA + ((S >> 1) & 1) * 16384 + (S & 1) * 8192;
      short* bD = lB + ((S >> 1) & 1) * 16384 + (S & 1) * 8192;
      stage_half(Ab + S * 32, lda, aD, wave, lane);
      stage_half(Bb + S * 32, ldb, bD, wave, lane);
    }
    // 3 groups (12 per-wave loads) allowed in flight; group G guaranteed landed
    asm volatile("s_waitcnt vmcnt(12)" ::: "memory");
    __builtin_amdgcn_s_barrier();
    asm volatile("" ::: "memory");

    const short* aS = lA + ((G >> 1) & 1) * 16384 + (G & 1) * 8192;
    const short* bS = lB + ((G >> 1) & 1) * 16384 + (G & 1) * 8192;
    bf16x8 a[8], b[4];
    #pragma unroll
    for (int j = 0; j < 4; ++j) {
      const int c = wn * 64 + j * 16 + (lane & 15);
      b[j] = *(const bf16x8*)(bS + c * 32 + (((g0 ^ c) & 3) << 3));
    }
    #pragma unroll
    for (int i = 0; i < 8; ++i) {
      const int r = wm * 128 + i * 16 + (lane & 15);
      a[i] = *(const bf16x8*)(aS + r * 32 + (((g0 ^ r) & 3) << 3));
    }
    __builtin_amdgcn_s_setprio(1);
    #pragma unroll
    for (int i = 0; i < 8; ++i)
      #pragma unroll
      for (int j = 0; j < 4; ++j)
        acc[i][j] = __builtin_amdgcn_mfma_f32_16x16x32_bf16(a[i], b[j], acc[i][j], 0, 0, 0);
    __builtin_amdgcn_s_setprio(0);

    asm volatile("" ::: "memory");
    __builtin_amdgcn_s_barrier();
  }

  // epilogue; C/D layout: col=lane&15, row=(lane>>4)*4+reg (m89)
  #pragma unroll
  for (int i = 0; i < 8; ++i)
    #pragma unroll
    for (int j = 0; j < 4; ++j)
      #pragma unroll
      for (int r = 0; r < 4; ++r) {
        const int rl = wm * 128 + i * 16 + ((lane >> 4) << 2) + r;
        const int cl = wn * 64 + j * 16 + (lane & 15);
        float v = acc[i][j][r];
        if (BIAS) v += bias[(long)zi * zsbias + bn + cl];
        if (RELU) v = v > 0.0f ? v : 0.0f;
        const long row = bm + rl;
        const long gi = (long)zi * zsc + row * ldc + bn + cl;
        if (GATE == 1) {
          const float x = b2f(eg[gi]) * v * 0.0625f;   // Qh*Kh/sqrt(256)
          v = 1.0f / (1.0f + __expf(-x));
        } else if (GATE == 2) {
          v = b2f(eg[gi]) * v;                          // gate*Vh
        }
        if (RESID) {
          ((float*)outv)[gi] = q[gi] - rep[gi] + v;
        } else {
          ((short*)outv)[gi] = f2b(v);
        }
      }
}

extern "C" void kernel_launch(void* const* d_in, const int* in_sizes, int n_in,
                              void* d_out, int out_size, void* d_ws, size_t ws_size,
                              hipStream_t stream) {
  const float* q   = (const float*)d_in[0];
  const float* rep = (const float*)d_in[1];
  const float* Wq  = (const float*)d_in[2];
  const float* Wk  = (const float*)d_in[3];
  const float* Wv  = (const float*)d_in[4];
  const float* W1  = (const float*)d_in[5];
  const float* b1  = (const float*)d_in[6];
  const float* W2  = (const float*)d_in[7];
  const float* b2  = (const float*)d_in[8];
  const float* Ws  = (const float*)d_in[9];
  float* out = (float*)d_out;

  const long NE = 67108864L;   // 65536 * 1024
  char* ws = (char*)d_ws;
  // 3 x 128 MiB slots:
  //   slotA: qb (cvt..G1)  -> zb (G3..M1)
  //   slotB: rb (cvt..G3)  -> ug (M2..F)
  //   slotC: gh (G1..G3)   -> h1 (M1..M2)
  short* qb  = (short*)(ws);
  short* rb  = (short*)(ws + NE * 2);
  short* gh  = (short*)(ws + NE * 4);
  short* zb  = qb;
  short* ugb = rb;
  short* h1b = gh;
  char*  wp  = ws + NE * 6;
  short* wqt = (short*)(wp);                 // 2 MiB each
  short* wkt = (short*)(wp + 2097152);
  short* wvt = (short*)(wp + 4194304);
  short* wst = (short*)(wp + 6291456);
  short* w1t = (short*)(wp + 8388608);       // 512 KiB
  short* w2t = (short*)(wp + 8912896);       // 512 KiB

  cvt_bf16<<<4096, 256, 0, stream>>>(q,   qb, NE);
  cvt_bf16<<<4096, 256, 0, stream>>>(rep, rb, NE);
  prep_weights<<<dim3(32, 32, 12), dim3(32, 8), 0, stream>>>(
      Wq, Wk, Wv, W1, W2, Ws, wqt, wkt, wvt, w1t, w2t, wst);

  // G1: Qh = q @ Wq  (bf16 -> gh)
  gemm_bf16<1024, 0, false, false, false, true><<<dim3(4, 256), 512, 0, stream>>>(
      qb, 1024, 0, wqt, 1024, 0, gh, 1024, 0, nullptr, 0, nullptr, nullptr, nullptr);
  // G2: gate = sigmoid(Qh * (rep @ Wk) / 16)  (in-place over gh)
  gemm_bf16<1024, 1, false, false, false, true><<<dim3(4, 256), 512, 0, stream>>>(
      rb, 1024, 0, wkt, 1024, 0, gh, 1024, 0, nullptr, 0, gh, nullptr, nullptr);
  // G3: z = gate * (rep @ Wv)  -> zb
  gemm_bf16<1024, 2, false, false, false, true><<<dim3(4, 256), 512, 0, stream>>>(
      rb, 1024, 0, wvt, 1024, 0, zb, 1024, 0, nullptr, 0, gh, nullptr, nullptr);

  // M1: h1 = relu(z @ W1 + b1), per head (head = blockIdx.z)
  gemm_bf16<256, 0, true, true, false, false><<<dim3(1, 256, 4), 512, 0, stream>>>(
      zb, 1024, 256, w1t, 256, 65536, h1b, 1024, 256, b1, 256, nullptr, nullptr, nullptr);
  // M2: ug = h1 @ W2 + b2, per head
  gemm_bf16<256, 0, false, true, false, false><<<dim3(1, 256, 4), 512, 0, stream>>>(
      h1b, 1024, 256, w2t, 256, 65536, ugb, 1024, 256, b2, 256, nullptr, nullptr, nullptr);
  // F: out = q - rep + ug @ Ws  (f32 epilogue)
  gemm_bf16<1024, 0, false, false, true, true><<<dim3(4, 256), 512, 0, stream>>>(
      ugb, 1024, 0, wst, 1024, 0, out, 1024, 0, nullptr, 0, nullptr, q, rep);
}

// Round 5
// 1112.760 us; speedup vs baseline: 1.2142x; 1.2142x over previous
//
#include <hip/hip_runtime.h>
#include <hip/hip_bf16.h>

// TreeHopNode: h = q - rep + (per-head MLP(sigmoid(Qh*Kh/16)*Vh)) @ Ws
// N=65536, E=1024, H=4, G=256, MLP=256. All GEMMs in bf16 MFMA, f32 accum.
//
// R5: faithful fine-grained 8-phase counted-vmcnt schedule (T3+T4+T5).
// 256x256 tile, 8 waves (2Mx4N), BK=64 split as 2 k-slices of 32.
// Phase (mh,ks) = {4-8 swizzled ds_read_b128 | stage 1 half-tile (2
// global_load_lds) | [vmcnt(4) at phase 4/8] | barrier | lgkmcnt(0) |
// setprio(1) | 16 MFMA | setprio(0) | barrier}.
// Stage ledger (verified WAR/RAW): tile t phases stage A1[t+1], B1[t+1],
// A0[t+2], B0[t+2]; every half staged 6 phases before first read; every
// LDS slot rewritten exactly one barrier after its last read.
// Swizzle: LDS slot s of row r holds global 16B-granule s^((r>>1)&3)
// -> read banks 2-way (free, m136). Fixes R4's 4-way conflict (64B rows).

typedef __attribute__((ext_vector_type(8))) short bf16x8;
typedef __attribute__((ext_vector_type(4))) float f32x4;
typedef __attribute__((ext_vector_type(4))) short short4v;

static __device__ __forceinline__ short f2b(float x) {
  __hip_bfloat16 h = __float2bfloat16(x);
  return __builtin_bit_cast(short, h);
}
static __device__ __forceinline__ float b2f(short s) {
  unsigned u = ((unsigned)(unsigned short)s) << 16;
  return __builtin_bit_cast(float, u);
}

// Stage one [256 rows x 32 k] bf16 half-tile into LDS (linear dest,
// pre-swizzled source granule). 2 x global_load_lds per thread.
static __device__ __forceinline__ void stage_half(
    const short* __restrict__ g, long ld, short* dst, int wave, int lane)
{
  const int rw = lane >> 2;                      // row within 16-row slab
  const int gg = (lane & 3) ^ ((rw >> 1) & 3);   // swizzled source granule
  const short* gl = g + (long)rw * ld + (gg << 3);
  #pragma unroll
  for (int j = 0; j < 2; ++j) {
    const int r0 = j * 128 + wave * 16;          // wave-uniform dest row
    __builtin_amdgcn_global_load_lds(
        (const __attribute__((address_space(1))) void*)(gl + (long)r0 * ld),
        (__attribute__((address_space(3))) void*)(dst + r0 * 32),
        16, 0, 0);
  }
}

// ---------------- convert f32 -> bf16, vectorized ----------------
__global__ void cvt_bf16(const float* __restrict__ in, short* __restrict__ out, long n) {
  long i = ((long)blockIdx.x * blockDim.x + threadIdx.x) * 4;
  const long stride = (long)gridDim.x * blockDim.x * 4;
  for (; i < n; i += stride) {
    float4 v = *(const float4*)(in + i);
    short4v o = { f2b(v.x), f2b(v.y), f2b(v.z), f2b(v.w) };
    *(short4v*)(out + i) = o;
  }
}

// ---------------- transpose + convert weights ----------------
__global__ void prep_weights(
    const float* __restrict__ Wq, const float* __restrict__ Wk, const float* __restrict__ Wv,
    const float* __restrict__ W1, const float* __restrict__ W2, const float* __restrict__ Ws,
    short* __restrict__ wqt, short* __restrict__ wkt, short* __restrict__ wvt,
    short* __restrict__ w1t, short* __restrict__ w2t, short* __restrict__ wst)
{
  const int job = blockIdx.z;
  const float* src; short* dst; int R, C;
  if (job < 3)       { src = (job==0)?Wq:((job==1)?Wk:Wv); dst = (job==0)?wqt:((job==1)?wkt:wvt); R = 1024; C = 1024; }
  else if (job == 3) { src = Ws; dst = wst; R = 1024; C = 1024; }
  else if (job < 8)  { int h = job-4; src = W1 + h*65536; dst = w1t + h*65536; R = 256; C = 256; }
  else               { int h = job-8; src = W2 + h*65536; dst = w2t + h*65536; R = 256; C = 256; }
  const int c0 = blockIdx.x * 32, r0 = blockIdx.y * 32;
  if (c0 >= C || r0 >= R) return;
  __shared__ float t[32][33];
  for (int i = threadIdx.y; i < 32; i += 8)
    t[i][threadIdx.x] = src[(long)(r0 + i) * C + c0 + threadIdx.x];
  __syncthreads();
  for (int i = threadIdx.y; i < 32; i += 8)
    dst[(long)(c0 + i) * R + r0 + threadIdx.x] = f2b(t[threadIdx.x][i]);
}

// ---------------- 256x256-tile bf16 GEMM, 8-phase pipeline -------------
// C = ep(A @ Bt^T); Bt stored [col][k]. blockIdx.z batches heads (strides).
// GATE==1: out = sigmoid(b2f(eg[gi]) * acc / 16)   (eg may alias out)
// GATE==2: out = b2f(eg[gi]) * acc
// RESID:   f32 out = q - rep + acc
// SWZ:     XCD-chunk block swizzle (requires gridDim.x*gridDim.y % 8 == 0)
template <int KDIM, int GATE, bool RELU, bool BIAS, bool RESID, bool SWZ>
__global__ __launch_bounds__(512, 2) void gemm_bf16(
    const short* __restrict__ A, long lda, long zsa,
    const short* __restrict__ Bt, long ldb, long zsb,
    void* __restrict__ outv, long ldc, long zsc,
    const float* __restrict__ bias, long zsbias,
    const short* __restrict__ eg,
    const float* __restrict__ q, const float* __restrict__ rep)
{
  __shared__ __align__(16) short lA[2][2][8192];   // [buf][kslice][256*32]
  __shared__ __align__(16) short lB[2][2][8192];
  const int lane = threadIdx.x & 63, wave = threadIdx.x >> 6;
  const int wm = wave >> 2, wn = wave & 3;         // 2M x 4N wave grid
  int bx = blockIdx.x, by = blockIdx.y;
  if (SWZ) {
    const int nbx = gridDim.x;
    const int flat = by * nbx + bx;
    const int chunk = (int)(gridDim.x * gridDim.y) >> 3;
    const int fid = (flat & 7) * chunk + (flat >> 3);
    bx = fid % nbx; by = fid / nbx;
  }
  const long bm = (long)by * 256;
  const int  bn = bx * 256;
  const int  zi = blockIdx.z;

  const short* Ab = A + (long)zi * zsa + bm * lda;
  const short* Bb = Bt + (long)zi * zsb + (long)bn * ldb;
  constexpr int NT = KDIM / 64;                    // K-tiles (even: 16 or 4)
  const int g0 = lane >> 4;                        // k-octet 0..3
  const int arow = wm * 128 + (lane & 15);
  const int bcol = wn * 64 + (lane & 15);

  auto stA = [&](int buf, int ks, int t) {
    const int tc = t < NT ? t : NT - 1;            // tail: clamp SOURCE only
    stage_half(Ab + tc * 64 + ks * 32, lda, &lA[buf][ks][0], wave, lane);
  };
  auto stB = [&](int buf, int ks, int t) {
    const int tc = t < NT ? t : NT - 1;
    stage_half(Bb + tc * 64 + ks * 32, ldb, &lB[buf][ks][0], wave, lane);
  };

  // prologue: tile0 all 4 halves + tile1 (A0,B0); leave last 2 halves in flight
  stA(0, 0, 0); stB(0, 0, 0); stA(0, 1, 0); stB(0, 1, 0);
  stA(1, 0, 1); stB(1, 0, 1);
  asm volatile("s_waitcnt vmcnt(4)" ::: "memory");
  __builtin_amdgcn_s_barrier();

  f32x4 acc[8][4] = {};
  bf16x8 b[4];

#define PHASE(BUF, MH, KS, LOADB, STAGE_STMT, CHECK)                        \
  {                                                                         \
    const short* aS = &lA[BUF][KS][0];                                      \
    const short* bS = &lB[BUF][KS][0];                                      \
    if (LOADB) {                                                            \
      _Pragma("unroll")                                                     \
      for (int j = 0; j < 4; ++j) {                                         \
        const int c = bcol + j * 16;                                        \
        b[j] = *(const bf16x8*)(bS + c * 32 + (((g0 ^ (c >> 1)) & 3) << 3));\
      }                                                                     \
    }                                                                       \
    bf16x8 a[4];                                                            \
    _Pragma("unroll")                                                       \
    for (int i2 = 0; i2 < 4; ++i2) {                                        \
      const int r = arow + (MH) * 64 + i2 * 16;                             \
      a[i2] = *(const bf16x8*)(aS + r * 32 + (((g0 ^ (r >> 1)) & 3) << 3)); \
    }                                                                       \
    STAGE_STMT;                                                             \
    if (CHECK) asm volatile("s_waitcnt vmcnt(4)" ::: "memory");             \
    asm volatile("" ::: "memory");                                          \
    __builtin_amdgcn_s_barrier();                                           \
    asm volatile("s_waitcnt lgkmcnt(0)" ::: "memory");                      \
    __builtin_amdgcn_sched_barrier(0);                                      \
    __builtin_amdgcn_s_setprio(1);                                          \
    _Pragma("unroll")                                                       \
    for (int i2 = 0; i2 < 4; ++i2)                                          \
      _Pragma("unroll")                                                     \
      for (int j = 0; j < 4; ++j)                                           \
        acc[(MH) * 4 + i2][j] = __builtin_amdgcn_mfma_f32_16x16x32_bf16(    \
            a[i2], b[j], acc[(MH) * 4 + i2][j], 0, 0, 0);                   \
    __builtin_amdgcn_s_setprio(0);                                          \
    asm volatile("" ::: "memory");                                          \
    __builtin_amdgcn_s_barrier();                                           \
  }

  for (int t = 0; t < NT; t += 2) {
    // tile t (buf0)
    PHASE(0, 0, 0, true,  stA(1, 1, t + 1), false)
    PHASE(0, 1, 0, false, stB(1, 1, t + 1), false)
    PHASE(0, 0, 1, true,  stA(0, 0, t + 2), false)
    PHASE(0, 1, 1, false, stB(0, 0, t + 2), true)
    // tile t+1 (buf1)
    PHASE(1, 0, 0, true,  stA(0, 1, t + 2), false)
    PHASE(1, 1, 0, false, stB(0, 1, t + 2), false)
    PHASE(1, 0, 1, true,  stA(1, 0, t + 3), false)
    PHASE(1, 1, 1, false, stB(1, 0, t + 3), true)
  }
#undef PHASE

  // epilogue; C/D layout: col=lane&15, row=(lane>>4)*4+reg (m89)
  #pragma unroll
  for (int i = 0; i < 8; ++i)
    #pragma unroll
    for (int j = 0; j < 4; ++j)
      #pragma unroll
      for (int r = 0; r < 4; ++r) {
        const int rl = wm * 128 + i * 16 + ((lane >> 4) << 2) + r;
        const int cl = wn * 64 + j * 16 + (lane & 15);
        float v = acc[i][j][r];
        if (BIAS) v += bias[(long)zi * zsbias + bn + cl];
        if (RELU) v = v > 0.0f ? v : 0.0f;
        const long row = bm + rl;
        const long gi = (long)zi * zsc + row * ldc + bn + cl;
        if (GATE == 1) {
          const float x = b2f(eg[gi]) * v * 0.0625f;   // Qh*Kh/sqrt(256)
          v = 1.0f / (1.0f + __expf(-x));
        } else if (GATE == 2) {
          v = b2f(eg[gi]) * v;                          // gate*Vh
        }
        if (RESID) {
          ((float*)outv)[gi] = q[gi] - rep[gi] + v;
        } else {
          ((short*)outv)[gi] = f2b(v);
        }
      }
}

extern "C" void kernel_launch(void* const* d_in, const int* in_sizes, int n_in,
                              void* d_out, int out_size, void* d_ws, size_t ws_size,
                              hipStream_t stream) {
  const float* q   = (const float*)d_in[0];
  const float* rep = (const float*)d_in[1];
  const float* Wq  = (const float*)d_in[2];
  const float* Wk  = (const float*)d_in[3];
  const float* Wv  = (const float*)d_in[4];
  const float* W1  = (const float*)d_in[5];
  const float* b1  = (const float*)d_in[6];
  const float* W2  = (const float*)d_in[7];
  const float* b2  = (const float*)d_in[8];
  const float* Ws  = (const float*)d_in[9];
  float* out = (float*)d_out;

  const long NE = 67108864L;   // 65536 * 1024
  char* ws = (char*)d_ws;
  // 3 x 128 MiB slots:
  //   slotA: qb (cvt..G1)  -> zb (G3..M1)
  //   slotB: rb (cvt..G3)  -> ug (M2..F)
  //   slotC: gh (G1..G3)   -> h1 (M1..M2)
  short* qb  = (short*)(ws);
  short* rb  = (short*)(ws + NE * 2);
  short* gh  = (short*)(ws + NE * 4);
  short* zb  = qb;
  short* ugb = rb;
  short* h1b = gh;
  char*  wp  = ws + NE * 6;
  short* wqt = (short*)(wp);                 // 2 MiB each
  short* wkt = (short*)(wp + 2097152);
  short* wvt = (short*)(wp + 4194304);
  short* wst = (short*)(wp + 6291456);
  short* w1t = (short*)(wp + 8388608);       // 512 KiB
  short* w2t = (short*)(wp + 8912896);       // 512 KiB

  cvt_bf16<<<4096, 256, 0, stream>>>(q,   qb, NE);
  cvt_bf16<<<4096, 256, 0, stream>>>(rep, rb, NE);
  prep_weights<<<dim3(32, 32, 12), dim3(32, 8), 0, stream>>>(
      Wq, Wk, Wv, W1, W2, Ws, wqt, wkt, wvt, w1t, w2t, wst);

  // G1: Qh = q @ Wq  (bf16 -> gh)
  gemm_bf16<1024, 0, false, false, false, true><<<dim3(4, 256), 512, 0, stream>>>(
      qb, 1024, 0, wqt, 1024, 0, gh, 1024, 0, nullptr, 0, nullptr, nullptr, nullptr);
  // G2: gate = sigmoid(Qh * (rep @ Wk) / 16)  (in-place over gh)
  gemm_bf16<1024, 1, false, false, false, true><<<dim3(4, 256), 512, 0, stream>>>(
      rb, 1024, 0, wkt, 1024, 0, gh, 1024, 0, nullptr, 0, gh, nullptr, nullptr);
  // G3: z = gate * (rep @ Wv)  -> zb
  gemm_bf16<1024, 2, false, false, false, true><<<dim3(4, 256), 512, 0, stream>>>(
      rb, 1024, 0, wvt, 1024, 0, zb, 1024, 0, nullptr, 0, gh, nullptr, nullptr);

  // M1: h1 = relu(z @ W1 + b1), per head (head = blockIdx.z)
  gemm_bf16<256, 0, true, true, false, false><<<dim3(1, 256, 4), 512, 0, stream>>>(
      zb, 1024, 256, w1t, 256, 65536, h1b, 1024, 256, b1, 256, nullptr, nullptr, nullptr);
  // M2: ug = h1 @ W2 + b2, per head
  gemm_bf16<256, 0, false, true, false, false><<<dim3(1, 256, 4), 512, 0, stream>>>(
      h1b, 1024, 256, w2t, 256, 65536, ugb, 1024, 256, b2, 256, nullptr, nullptr, nullptr);
  // F: out = q - rep + ug @ Ws  (f32 epilogue)
  gemm_bf16<1024, 0, false, false, true, true><<<dim3(4, 256), 512, 0, stream>>>(
      ugb, 1024, 0, wst, 1024, 0, out, 1024, 0, nullptr, 0, nullptr, q, rep);
}

// Round 6
// 1043.705 us; speedup vs baseline: 1.2945x; 1.0662x over previous
//
#include <hip/hip_runtime.h>
#include <hip/hip_bf16.h>

// TreeHopNode: h = q - rep + (per-head MLP(sigmoid(Qh*Kh/16)*Vh)) @ Ws
// N=65536, E=1024, H=4, G=256, MLP=256. All GEMMs bf16 MFMA 16x16x32, f32 acc.
//
// R6 vs R5:
//  - G2+G3 merged into gemm_g23 (dual acc: Kh and Vh from the same staged rb
//    tile; epilogue z = sigmoid(Qh*Kh/16)*Vh reads Qh once) -> kills the gate
//    round-trip (-256MB) and the duplicate rb staging.
//  - F epilogue residual from bf16 qb/rb (-256MB fetch) instead of f32 q/rep.
//  - workspace: 4 x 128MB slots (qb, rb persist to F).
// Schedule unchanged: 256-wide 8-phase counted-vmcnt pipeline (R5, verified).

typedef __attribute__((ext_vector_type(8))) short bf16x8;
typedef __attribute__((ext_vector_type(4))) float f32x4;
typedef __attribute__((ext_vector_type(4))) short short4v;

static __device__ __forceinline__ short f2b(float x) {
  __hip_bfloat16 h = __float2bfloat16(x);
  return __builtin_bit_cast(short, h);
}
static __device__ __forceinline__ float b2f(short s) {
  unsigned u = ((unsigned)(unsigned short)s) << 16;
  return __builtin_bit_cast(float, u);
}

// Stage one [256 rows x 32 k] bf16 half-tile into LDS (linear dest,
// pre-swizzled source granule; LDS slot s of row r = global granule s^((r>>1)&3)).
static __device__ __forceinline__ void stage_half(
    const short* __restrict__ g, long ld, short* dst, int wave, int lane)
{
  const int rw = lane >> 2;
  const int gg = (lane & 3) ^ ((rw >> 1) & 3);
  const short* gl = g + (long)rw * ld + (gg << 3);
  #pragma unroll
  for (int j = 0; j < 2; ++j) {
    const int r0 = j * 128 + wave * 16;
    __builtin_amdgcn_global_load_lds(
        (const __attribute__((address_space(1))) void*)(gl + (long)r0 * ld),
        (__attribute__((address_space(3))) void*)(dst + r0 * 32),
        16, 0, 0);
  }
}

// Same for a [128 rows x 32 k] half-tile (one inst/thread).
static __device__ __forceinline__ void stage_half128(
    const short* __restrict__ g, long ld, short* dst, int wave, int lane)
{
  const int rw = lane >> 2;
  const int gg = (lane & 3) ^ ((rw >> 1) & 3);
  const int r0 = wave * 16;
  __builtin_amdgcn_global_load_lds(
      (const __attribute__((address_space(1))) void*)(g + (long)(r0 + rw) * ld + (gg << 3)),
      (__attribute__((address_space(3))) void*)(dst + r0 * 32),
      16, 0, 0);
}

// ---------------- convert f32 -> bf16, vectorized ----------------
__global__ void cvt_bf16(const float* __restrict__ in, short* __restrict__ out, long n) {
  long i = ((long)blockIdx.x * blockDim.x + threadIdx.x) * 4;
  const long stride = (long)gridDim.x * blockDim.x * 4;
  for (; i < n; i += stride) {
    float4 v = *(const float4*)(in + i);
    short4v o = { f2b(v.x), f2b(v.y), f2b(v.z), f2b(v.w) };
    *(short4v*)(out + i) = o;
  }
}

// ---------------- transpose + convert weights ----------------
__global__ void prep_weights(
    const float* __restrict__ Wq, const float* __restrict__ Wk, const float* __restrict__ Wv,
    const float* __restrict__ W1, const float* __restrict__ W2, const float* __restrict__ Ws,
    short* __restrict__ wqt, short* __restrict__ wkt, short* __restrict__ wvt,
    short* __restrict__ w1t, short* __restrict__ w2t, short* __restrict__ wst)
{
  const int job = blockIdx.z;
  const float* src; short* dst; int R, C;
  if (job < 3)       { src = (job==0)?Wq:((job==1)?Wk:Wv); dst = (job==0)?wqt:((job==1)?wkt:wvt); R = 1024; C = 1024; }
  else if (job == 3) { src = Ws; dst = wst; R = 1024; C = 1024; }
  else if (job < 8)  { int h = job-4; src = W1 + h*65536; dst = w1t + h*65536; R = 256; C = 256; }
  else               { int h = job-8; src = W2 + h*65536; dst = w2t + h*65536; R = 256; C = 256; }
  const int c0 = blockIdx.x * 32, r0 = blockIdx.y * 32;
  if (c0 >= C || r0 >= R) return;
  __shared__ float t[32][33];
  for (int i = threadIdx.y; i < 32; i += 8)
    t[i][threadIdx.x] = src[(long)(r0 + i) * C + c0 + threadIdx.x];
  __syncthreads();
  for (int i = threadIdx.y; i < 32; i += 8)
    dst[(long)(c0 + i) * R + r0 + threadIdx.x] = f2b(t[threadIdx.x][i]);
}

// ---------------- 256x256-tile bf16 GEMM, 8-phase pipeline -------------
// C = ep(A @ Bt^T); Bt stored [col][k]. blockIdx.z batches heads (strides).
// RESID: f32 out = b2f(qres[gi]) - b2f(rres[gi]) + acc
template <int KDIM, bool RELU, bool BIAS, bool RESID, bool SWZ>
__global__ __launch_bounds__(512, 2) void gemm_bf16(
    const short* __restrict__ A, long lda, long zsa,
    const short* __restrict__ Bt, long ldb, long zsb,
    void* __restrict__ outv, long ldc, long zsc,
    const float* __restrict__ bias, long zsbias,
    const short* __restrict__ qres, const short* __restrict__ rres)
{
  __shared__ __align__(16) short lA[2][2][8192];   // [buf][kslice][256*32]
  __shared__ __align__(16) short lB[2][2][8192];
  const int lane = threadIdx.x & 63, wave = threadIdx.x >> 6;
  const int wm = wave >> 2, wn = wave & 3;         // 2M x 4N wave grid
  int bx = blockIdx.x, by = blockIdx.y;
  if (SWZ) {
    const int nbx = gridDim.x;
    const int flat = by * nbx + bx;
    const int chunk = (int)(gridDim.x * gridDim.y) >> 3;
    const int fid = (flat & 7) * chunk + (flat >> 3);
    bx = fid % nbx; by = fid / nbx;
  }
  const long bm = (long)by * 256;
  const int  bn = bx * 256;
  const int  zi = blockIdx.z;

  const short* Ab = A + (long)zi * zsa + bm * lda;
  const short* Bb = Bt + (long)zi * zsb + (long)bn * ldb;
  constexpr int NT = KDIM / 64;
  const int g0 = lane >> 4;
  const int arow = wm * 128 + (lane & 15);
  const int bcol = wn * 64 + (lane & 15);

  auto stA = [&](int buf, int ks, int t) {
    const int tc = t < NT ? t : NT - 1;            // tail: clamp SOURCE only
    stage_half(Ab + tc * 64 + ks * 32, lda, &lA[buf][ks][0], wave, lane);
  };
  auto stB = [&](int buf, int ks, int t) {
    const int tc = t < NT ? t : NT - 1;
    stage_half(Bb + tc * 64 + ks * 32, ldb, &lB[buf][ks][0], wave, lane);
  };

  stA(0, 0, 0); stB(0, 0, 0); stA(0, 1, 0); stB(0, 1, 0);
  stA(1, 0, 1); stB(1, 0, 1);
  asm volatile("s_waitcnt vmcnt(4)" ::: "memory");
  __builtin_amdgcn_s_barrier();

  f32x4 acc[8][4] = {};
  bf16x8 b[4];

#define PHASE(BUF, MH, KS, LOADB, STAGE_STMT, CHECK)                        \
  {                                                                         \
    const short* aS = &lA[BUF][KS][0];                                      \
    const short* bS = &lB[BUF][KS][0];                                      \
    if (LOADB) {                                                            \
      _Pragma("unroll")                                                     \
      for (int j = 0; j < 4; ++j) {                                         \
        const int c = bcol + j * 16;                                        \
        b[j] = *(const bf16x8*)(bS + c * 32 + (((g0 ^ (c >> 1)) & 3) << 3));\
      }                                                                     \
    }                                                                       \
    bf16x8 a[4];                                                            \
    _Pragma("unroll")                                                       \
    for (int i2 = 0; i2 < 4; ++i2) {                                        \
      const int r = arow + (MH) * 64 + i2 * 16;                             \
      a[i2] = *(const bf16x8*)(aS + r * 32 + (((g0 ^ (r >> 1)) & 3) << 3)); \
    }                                                                       \
    STAGE_STMT;                                                             \
    if (CHECK) asm volatile("s_waitcnt vmcnt(4)" ::: "memory");             \
    asm volatile("" ::: "memory");                                          \
    __builtin_amdgcn_s_barrier();                                           \
    asm volatile("s_waitcnt lgkmcnt(0)" ::: "memory");                      \
    __builtin_amdgcn_sched_barrier(0);                                      \
    __builtin_amdgcn_s_setprio(1);                                          \
    _Pragma("unroll")                                                       \
    for (int i2 = 0; i2 < 4; ++i2)                                          \
      _Pragma("unroll")                                                     \
      for (int j = 0; j < 4; ++j)                                           \
        acc[(MH) * 4 + i2][j] = __builtin_amdgcn_mfma_f32_16x16x32_bf16(    \
            a[i2], b[j], acc[(MH) * 4 + i2][j], 0, 0, 0);                   \
    __builtin_amdgcn_s_setprio(0);                                          \
    asm volatile("" ::: "memory");                                          \
    __builtin_amdgcn_s_barrier();                                           \
  }

  for (int t = 0; t < NT; t += 2) {
    PHASE(0, 0, 0, true,  stA(1, 1, t + 1), false)
    PHASE(0, 1, 0, false, stB(1, 1, t + 1), false)
    PHASE(0, 0, 1, true,  stA(0, 0, t + 2), false)
    PHASE(0, 1, 1, false, stB(0, 0, t + 2), true)
    PHASE(1, 0, 0, true,  stA(0, 1, t + 2), false)
    PHASE(1, 1, 0, false, stB(0, 1, t + 2), false)
    PHASE(1, 0, 1, true,  stA(1, 0, t + 3), false)
    PHASE(1, 1, 1, false, stB(1, 0, t + 3), true)
  }
#undef PHASE

  // epilogue; C/D layout: col=lane&15, row=(lane>>4)*4+reg (m89)
  #pragma unroll
  for (int i = 0; i < 8; ++i)
    #pragma unroll
    for (int j = 0; j < 4; ++j)
      #pragma unroll
      for (int r = 0; r < 4; ++r) {
        const int rl = wm * 128 + i * 16 + ((lane >> 4) << 2) + r;
        const int cl = wn * 64 + j * 16 + (lane & 15);
        float v = acc[i][j][r];
        if (BIAS) v += bias[(long)zi * zsbias + bn + cl];
        if (RELU) v = v > 0.0f ? v : 0.0f;
        const long row = bm + rl;
        const long gi = (long)zi * zsc + row * ldc + bn + cl;
        if (RESID) {
          ((float*)outv)[gi] = b2f(qres[gi]) - b2f(rres[gi]) + v;
        } else {
          ((short*)outv)[gi] = f2b(v);
        }
      }
}

// ------------- merged G2+G3: z = sigmoid(Qh*Kh/16) * Vh -------------
// 256x128 tile, dual accumulators (Kh, Vh) sharing the staged A (rep) tile.
// Same 8-phase counted-vmcnt ledger as gemm_bf16 (B stages split Bk/Bv).
__global__ __launch_bounds__(512, 2) void gemm_g23(
    const short* __restrict__ rb,    // A: rep bf16 [65536][1024]
    const short* __restrict__ wkt,   // Bk [col][k]
    const short* __restrict__ wvt,   // Bv [col][k]
    const short* __restrict__ gh,    // Qh bf16 [65536][1024]
    short* __restrict__ zb)          // z bf16 out
{
  __shared__ __align__(16) short lA[2][2][8192];   // 64KB: 256 rows x 32k
  __shared__ __align__(16) short lK[2][2][4096];   // 32KB: 128 cols x 32k
  __shared__ __align__(16) short lV[2][2][4096];   // 32KB
  const int lane = threadIdx.x & 63, wave = threadIdx.x >> 6;
  const int wm = wave >> 2, wn = wave & 3;         // per-wave out: 128 x 32
  int bx = blockIdx.x, by = blockIdx.y;
  {
    const int flat = by * 8 + bx;                  // gridDim.x == 8
    const int chunk = (int)(gridDim.x * gridDim.y) >> 3;
    const int fid = (flat & 7) * chunk + (flat >> 3);
    bx = fid & 7; by = fid >> 3;
  }
  const long bm = (long)by * 256;
  const int  bn = bx * 128;

  const short* Ab = rb + bm * 1024;
  const short* Kb = wkt + (long)bn * 1024;
  const short* Vb = wvt + (long)bn * 1024;
  constexpr int NT = 16;                           // K = 1024
  const int g0 = lane >> 4;
  const int arow = wm * 128 + (lane & 15);
  const int bcol = wn * 32 + (lane & 15);

  auto stA = [&](int buf, int ks, int t) {
    const int tc = t < NT ? t : NT - 1;
    stage_half(Ab + tc * 64 + ks * 32, 1024, &lA[buf][ks][0], wave, lane);
  };
  auto stK = [&](int buf, int ks, int t) {
    const int tc = t < NT ? t : NT - 1;
    stage_half128(Kb + tc * 64 + ks * 32, 1024, &lK[buf][ks][0], wave, lane);
  };
  auto stV = [&](int buf, int ks, int t) {
    const int tc = t < NT ? t : NT - 1;
    stage_half128(Vb + tc * 64 + ks * 32, 1024, &lV[buf][ks][0], wave, lane);
  };

  // prologue: buf0 complete (8 insts), buf1 ks0 in flight (4 insts)
  stA(0, 0, 0); stK(0, 0, 0); stV(0, 0, 0);
  stA(0, 1, 0); stK(0, 1, 0); stV(0, 1, 0);
  stA(1, 0, 1); stK(1, 0, 1); stV(1, 0, 1);
  asm volatile("s_waitcnt vmcnt(4)" ::: "memory");
  __builtin_amdgcn_s_barrier();

  f32x4 ack[8][2] = {};
  f32x4 acv[8][2] = {};
  bf16x8 bk[2], bv[2];

#define PHASEG(BUF, MH, KS, LOADB, STAGE_STMT, CHECK)                       \
  {                                                                         \
    const short* aS = &lA[BUF][KS][0];                                      \
    if (LOADB) {                                                            \
      _Pragma("unroll")                                                     \
      for (int j = 0; j < 2; ++j) {                                         \
        const int c = bcol + j * 16;                                        \
        const int so = c * 32 + (((g0 ^ (c >> 1)) & 3) << 3);               \
        bk[j] = *(const bf16x8*)(&lK[BUF][KS][0] + so);                     \
        bv[j] = *(const bf16x8*)(&lV[BUF][KS][0] + so);                     \
      }                                                                     \
    }                                                                       \
    bf16x8 a[4];                                                            \
    _Pragma("unroll")                                                       \
    for (int i2 = 0; i2 < 4; ++i2) {                                        \
      const int r = arow + (MH) * 64 + i2 * 16;                             \
      a[i2] = *(const bf16x8*)(aS + r * 32 + (((g0 ^ (r >> 1)) & 3) << 3)); \
    }                                                                       \
    STAGE_STMT;                                                             \
    if (CHECK) asm volatile("s_waitcnt vmcnt(4)" ::: "memory");             \
    asm volatile("" ::: "memory");                                          \
    __builtin_amdgcn_s_barrier();                                           \
    asm volatile("s_waitcnt lgkmcnt(0)" ::: "memory");                      \
    __builtin_amdgcn_sched_barrier(0);                                      \
    __builtin_amdgcn_s_setprio(1);                                          \
    _Pragma("unroll")                                                       \
    for (int i2 = 0; i2 < 4; ++i2)                                          \
      _Pragma("unroll")                                                     \
      for (int j = 0; j < 2; ++j) {                                         \
        ack[(MH) * 4 + i2][j] = __builtin_amdgcn_mfma_f32_16x16x32_bf16(    \
            a[i2], bk[j], ack[(MH) * 4 + i2][j], 0, 0, 0);                  \
        acv[(MH) * 4 + i2][j] = __builtin_amdgcn_mfma_f32_16x16x32_bf16(    \
            a[i2], bv[j], acv[(MH) * 4 + i2][j], 0, 0, 0);                  \
      }                                                                     \
    __builtin_amdgcn_s_setprio(0);                                          \
    asm volatile("" ::: "memory");                                          \
    __builtin_amdgcn_s_barrier();                                           \
  }

  for (int t = 0; t < NT; t += 2) {
    PHASEG(0, 0, 0, true,  stA(1, 1, t + 1), false)
    PHASEG(0, 1, 0, false, { stK(1, 1, t + 1); stV(1, 1, t + 1); }, false)
    PHASEG(0, 0, 1, true,  stA(0, 0, t + 2), false)
    PHASEG(0, 1, 1, false, { stK(0, 0, t + 2); stV(0, 0, t + 2); }, true)
    PHASEG(1, 0, 0, true,  stA(0, 1, t + 2), false)
    PHASEG(1, 1, 0, false, { stK(0, 1, t + 2); stV(0, 1, t + 2); }, false)
    PHASEG(1, 0, 1, true,  stA(1, 0, t + 3), false)
    PHASEG(1, 1, 1, false, { stK(1, 0, t + 3); stV(1, 0, t + 3); }, true)
  }
#undef PHASEG

  // epilogue: z = sigmoid(Qh * Kh / 16) * Vh
  #pragma unroll
  for (int i = 0; i < 8; ++i)
    #pragma unroll
    for (int j = 0; j < 2; ++j)
      #pragma unroll
      for (int r = 0; r < 4; ++r) {
        const int rl = wm * 128 + i * 16 + ((lane >> 4) << 2) + r;
        const int cl = wn * 32 + j * 16 + (lane & 15);
        const long gi = (bm + rl) * 1024 + bn + cl;
        const float x = b2f(gh[gi]) * ack[i][j][r] * 0.0625f;
        const float gate = 1.0f / (1.0f + __expf(-x));
        zb[gi] = f2b(gate * acv[i][j][r]);
      }
}

extern "C" void kernel_launch(void* const* d_in, const int* in_sizes, int n_in,
                              void* d_out, int out_size, void* d_ws, size_t ws_size,
                              hipStream_t stream) {
  const float* q   = (const float*)d_in[0];
  const float* rep = (const float*)d_in[1];
  const float* Wq  = (const float*)d_in[2];
  const float* Wk  = (const float*)d_in[3];
  const float* Wv  = (const float*)d_in[4];
  const float* W1  = (const float*)d_in[5];
  const float* b1  = (const float*)d_in[6];
  const float* W2  = (const float*)d_in[7];
  const float* b2  = (const float*)d_in[8];
  const float* Ws  = (const float*)d_in[9];
  float* out = (float*)d_out;

  const long NE = 67108864L;   // 65536 * 1024
  char* ws = (char*)d_ws;
  // 4 x 128 MiB slots:
  //   s0: qb  (cvt .. F)
  //   s1: rb  (cvt .. F)
  //   s2: gh  (G1 .. G23), then h1 (M1 .. M2)
  //   s3: zb  (G23 .. M1), then ug (M2 .. F)
  short* qb  = (short*)(ws);
  short* rb  = (short*)(ws + NE * 2);
  short* gh  = (short*)(ws + NE * 4);
  short* zb  = (short*)(ws + NE * 6);
  short* h1b = gh;
  short* ugb = zb;
  char*  wp  = ws + NE * 8;
  short* wqt = (short*)(wp);                 // 2 MiB each
  short* wkt = (short*)(wp + 2097152);
  short* wvt = (short*)(wp + 4194304);
  short* wst = (short*)(wp + 6291456);
  short* w1t = (short*)(wp + 8388608);       // 512 KiB
  short* w2t = (short*)(wp + 8912896);       // 512 KiB

  cvt_bf16<<<4096, 256, 0, stream>>>(q,   qb, NE);
  cvt_bf16<<<4096, 256, 0, stream>>>(rep, rb, NE);
  prep_weights<<<dim3(32, 32, 12), dim3(32, 8), 0, stream>>>(
      Wq, Wk, Wv, W1, W2, Ws, wqt, wkt, wvt, w1t, w2t, wst);

  // G1: Qh = q @ Wq  (bf16 -> gh)
  gemm_bf16<1024, false, false, false, true><<<dim3(4, 256), 512, 0, stream>>>(
      qb, 1024, 0, wqt, 1024, 0, gh, 1024, 0, nullptr, 0, nullptr, nullptr);
  // G23: z = sigmoid(Qh * (rep@Wk) / 16) * (rep@Wv)  -> zb
  gemm_g23<<<dim3(8, 256), 512, 0, stream>>>(rb, wkt, wvt, gh, zb);

  // M1: h1 = relu(z @ W1 + b1), per head (head = blockIdx.z)
  gemm_bf16<256, true, true, false, false><<<dim3(1, 256, 4), 512, 0, stream>>>(
      zb, 1024, 256, w1t, 256, 65536, h1b, 1024, 256, b1, 256, nullptr, nullptr);
  // M2: ug = h1 @ W2 + b2, per head
  gemm_bf16<256, false, true, false, false><<<dim3(1, 256, 4), 512, 0, stream>>>(
      h1b, 1024, 256, w2t, 256, 65536, ugb, 1024, 256, b2, 256, nullptr, nullptr);
  // F: out = (q - rep) + ug @ Ws   (residual from bf16 qb/rb)
  gemm_bf16<1024, false, false, true, true><<<dim3(4, 256), 512, 0, stream>>>(
      ugb, 1024, 0, wst, 1024, 0, out, 1024, 0, nullptr, 0, qb, rb);
}